// Round 6
// baseline (262.249 us; speedup 1.0000x reference)
//
#include <hip/hip_runtime.h>
#include <stdint.h>

typedef __attribute__((ext_vector_type(8))) short short8;
typedef __attribute__((ext_vector_type(4))) float f32x4;
typedef __attribute__((ext_vector_type(4))) float f4;
typedef __attribute__((ext_vector_type(4))) ushort us4;

#define AS1 __attribute__((address_space(1)))
#define AS3 __attribute__((address_space(3)))

__device__ __forceinline__ ushort f2bf(float f) {
  uint u = __builtin_bit_cast(uint, f);
  u += 0x7fffu + ((u >> 16) & 1u);
  return (ushort)(u >> 16);
}

// ---------------- fused f32 -> bf16 conversion (x, wi, wo in one launch) ----
__global__ void cvt_all(const float* __restrict__ x, const float* __restrict__ wi,
                        const float* __restrict__ wo, ushort* __restrict__ xb,
                        ushort* __restrict__ wib, ushort* __restrict__ wob) {
  const int n_x = (16384 * 1024) / 4;
  const int n_wi = (3072 * 1024) / 4;
  const int n_wo = (1024 * 1024) / 4;
  const int n_tot = n_x + n_wi + n_wo;
  int i = blockIdx.x * blockDim.x + threadIdx.x;
  int stride = gridDim.x * blockDim.x;
  for (; i < n_tot; i += stride) {
    const float* src;
    ushort* dst;
    int idx;
    if (i < n_x) {
      src = x; dst = xb; idx = i;
    } else if (i < n_x + n_wi) {
      src = wi; dst = wib; idx = i - n_x;
    } else {
      src = wo; dst = wob; idx = i - n_x - n_wi;
    }
    f4 v = ((const f4*)src)[idx];
    us4 o;
    o[0] = f2bf(v[0]); o[1] = f2bf(v[1]); o[2] = f2bf(v[2]); o[3] = f2bf(v[3]);
    ((us4*)dst)[idx] = o;
  }
}

// ---------------- persistent 256x256-tile 8-phase GEMM ----------------
// C[M,N] = A[M,1024] * B[N,1024]^T + bias.  K=1024 hardcoded (NT=16).
// 8 waves (2M x 4N), BK=64, double-buffered LDS, row-XOR swizzle
// physical_byte = logical_byte ^ ((row&7)<<4).  Round-2 verified phase
// schedule; block is PERSISTENT over NTILE consecutive output tiles: the
// half-tile staging index j runs over 4*16*NTILE half-tiles continuously,
// so prologue fill + vmcnt drain happen once per block, not per tile.
// Tile mapping row-major within XCD chunk (round-2: best FETCH/time).

__device__ __forceinline__ void stage_half(const ushort* __restrict__ g,
                                           int row0, int k0, char* ldsbase, int tid) {
#pragma unroll
  for (int i = 0; i < 2; ++i) {
    uint chunk = i * 512 + tid;              // physical 16B chunk in 16KB half-tile
    uint Q = chunk << 4;
    uint L = Q ^ (((Q >> 7) & 7u) << 4);     // logical byte (involution, row-preserving)
    uint row = L >> 7;                       // 0..127
    uint kb = L & 127u;
    const char* gp = (const char*)(g + (size_t)(row0 + (int)row) * 1024 + k0) + kb;
    char* lp = ldsbase + ((i * 512 + (tid & ~63)) << 4);  // wave-uniform base
    __builtin_amdgcn_global_load_lds((const AS1 void*)gp, (AS3 void*)lp, 16, 0, 0);
  }
}

template <int GN>
__device__ __forceinline__ void stage_g(int j, int Tbase, const ushort* __restrict__ A,
                                        const ushort* __restrict__ Bw,
                                        char* sA, char* sB, int tid) {
  int tile = j >> 6;                         // 4*NT = 64 half-tiles per output tile
  int jj = j & 63;
  int t = jj >> 2, h = jj & 3;               // h: 0,1 = B halves; 2,3 = A halves
  int T = Tbase + tile;
  int bm = T / GN, bn = T % GN;              // compile-time GN -> magic mul
  int k0 = t << 6;
  char* base = ((h < 2) ? sB : sA) + ((((uint)j >> 2) & 1u) << 15) + ((h & 1) << 14);
  const ushort* g = (h < 2) ? Bw : A;
  int row0 = (((h < 2) ? bn : bm) << 8) + ((h & 1) << 7);
  stage_half(g, row0, k0, base, tid);
}

template <int OUT_F32, int GN, int NTILE>
__global__ __launch_bounds__(512, 1) void gemm256p(const ushort* __restrict__ A,
                                                   const ushort* __restrict__ Bw,
                                                   const float* __restrict__ bias,
                                                   void* __restrict__ Cout, int N) {
  __shared__ char sA[65536];
  __shared__ char sB[65536];
  const int tid = threadIdx.x;
  const int lane = tid & 63, l15 = lane & 15, lk = lane >> 4;
  const int w = tid >> 6;
  const int wm = w >> 2, wn = w & 3;
  const int TOT = 16 * NTILE;                // total K-tile phases per block

  // XCD-aware chunking (grid %8==0), then NTILE consecutive tiles per block.
  int q8 = gridDim.x >> 3;
  int g = blockIdx.x;
  int gs = (g & 7) * q8 + (g >> 3);
  const int Tbase = gs * NTILE;

  f32x4 acc[8][4];
  f32x4 zero = {0.f, 0.f, 0.f, 0.f};
#pragma unroll
  for (int i = 0; i < 8; ++i)
#pragma unroll
    for (int j = 0; j < 4; ++j) acc[i][j] = zero;

  // prologue: stage half-tiles 0..6 (K-tile 0 complete + 3 of K-tile 1)
#pragma unroll
  for (int j = 0; j < 7; ++j) stage_g<GN>(j, Tbase, A, Bw, sA, sB, tid);
  asm volatile("s_waitcnt vmcnt(6)" ::: "memory");
  __builtin_amdgcn_s_barrier();

#pragma unroll 1
  for (int tg = 0; tg < TOT; ++tg) {
    const char* bA = sA + ((tg & 1) << 15);
    const char* bB = sB + ((tg & 1) << 15);
    short8 bfr[4][2];
#pragma unroll
    for (int qd = 0; qd < 4; ++qd) {
      short8 afr[2][2];
      if (qd == 0) {
#pragma unroll
        for (int ni = 0; ni < 4; ++ni)
#pragma unroll
          for (int kk = 0; kk < 2; ++kk) {
            uint row = (uint)(wn * 64 + ni * 16 + l15);
            uint byte = (row << 7) + (kk << 6) + (lk << 4);
            bfr[ni][kk] = *(const short8*)&bB[byte ^ ((row & 7u) << 4)];
          }
      }
#pragma unroll
      for (int mi = 0; mi < 2; ++mi)
#pragma unroll
        for (int kk = 0; kk < 2; ++kk) {
          uint row = (uint)(wm * 128 + (qd * 2 + mi) * 16 + l15);
          uint byte = (row << 7) + (kk << 6) + (lk << 4);
          afr[mi][kk] = *(const short8*)&bA[byte ^ ((row & 7u) << 4)];
        }
      int j = 4 * tg + qd + 7;
      if (j < 4 * TOT) stage_g<GN>(j, Tbase, A, Bw, sA, sB, tid);
      if (qd == 3) {
        if (tg < TOT - 2) asm volatile("s_waitcnt vmcnt(6)" ::: "memory");
        else if (tg == TOT - 2) asm volatile("s_waitcnt vmcnt(0)" ::: "memory");
      }
      __builtin_amdgcn_s_barrier();
      asm volatile("s_waitcnt lgkmcnt(0)" ::: "memory");
      __builtin_amdgcn_s_setprio(1);
#pragma unroll
      for (int kk = 0; kk < 2; ++kk)
#pragma unroll
        for (int mi = 0; mi < 2; ++mi)
#pragma unroll
          for (int ni = 0; ni < 4; ++ni)
            acc[qd * 2 + mi][ni] = __builtin_amdgcn_mfma_f32_16x16x32_bf16(
                afr[mi][kk], bfr[ni][kk], acc[qd * 2 + mi][ni], 0, 0, 0);
      __builtin_amdgcn_s_setprio(0);
      __builtin_amdgcn_s_barrier();
    }

    if ((tg & 15) == 15) {
      // tile finished: write C (C/D layout: col=lane&15, row=(lane>>4)*4+reg)
      int T = Tbase + (tg >> 4);
      int arow0 = (T / GN) << 8, brow0 = (T % GN) << 8;
#pragma unroll
      for (int m = 0; m < 8; ++m)
#pragma unroll
        for (int ni = 0; ni < 4; ++ni)
#pragma unroll
          for (int r = 0; r < 4; ++r) {
            int row = arow0 + wm * 128 + m * 16 + lk * 4 + r;
            int col = brow0 + wn * 64 + ni * 16 + l15;
            float v = acc[m][ni][r] + bias[col];
            if constexpr (OUT_F32)
              ((float*)Cout)[(size_t)row * N + col] = v;
            else
              ((ushort*)Cout)[(size_t)row * N + col] = f2bf(v);
          }
#pragma unroll
      for (int i = 0; i < 8; ++i)
#pragma unroll
        for (int jz = 0; jz < 4; ++jz) acc[i][jz] = zero;
    }
  }
}

// ---------------- cron-root block-sparse attention ----------------
// qkv: [B*S][3072] bf16, cols: q = h*64+d, k = 1024 + h*64+d, v = 2048 + h*64+d
// grid = B*H*nb = 4096 blocks of 256 threads; each wave = 16 query rows.
__global__ __launch_bounds__(256) void cron_attn(const ushort* __restrict__ qkv,
                                                 ushort* __restrict__ aout) {
  const int S = 4096, CQ = 3072;
  int bid = blockIdx.x;
  int n = bid & 63;
  int h = (bid >> 6) & 15;
  int b = bid >> 10;
  int tid = threadIdx.x;
  int w = tid >> 6, lane = tid & 63, l15 = lane & 15, lk = lane >> 4;

  const ushort* qp = qkv + (size_t)b * S * CQ + h * 64;
  const ushort* kp = qp + 1024;
  const ushort* vp = qp + 2048;

  __shared__ char vT[16384];    // [64 d][128 key] bf16, swizzled 256B rows
  __shared__ char pL[4][4096];  // per-wave [16 q][128 key] bf16, swizzled

  // ---- stage V^T (concat local block + 64 summary slots) ----
  {
    int r = tid >> 1;     // concat key index 0..127
    int half = tid & 1;   // d half: half*32 .. +31
    int srow = (r < 64) ? (n * 64 + r) : ((r - 64) * 64 + 63);
    const ushort* src = vp + (size_t)srow * CQ + half * 32;
    short8 vv0 = ((const short8*)src)[0];
    short8 vv1 = ((const short8*)src)[1];
    short8 vv2 = ((const short8*)src)[2];
    short8 vv3 = ((const short8*)src)[3];
#pragma unroll
    for (int j = 0; j < 8; ++j) {
      int d0 = half * 32 + j;
      *(short*)&vT[(uint)(d0 * 256 + r * 2) ^ (((uint)d0 & 7u) << 4)] = vv0[j];
      int d1 = half * 32 + 8 + j;
      *(short*)&vT[(uint)(d1 * 256 + r * 2) ^ (((uint)d1 & 7u) << 4)] = vv1[j];
      int d2 = half * 32 + 16 + j;
      *(short*)&vT[(uint)(d2 * 256 + r * 2) ^ (((uint)d2 & 7u) << 4)] = vv2[j];
      int d3 = half * 32 + 24 + j;
      *(short*)&vT[(uint)(d3 * 256 + r * 2) ^ (((uint)d3 & 7u) << 4)] = vv3[j];
    }
  }
  __syncthreads();

  // ---- Q fragments (A operand): row = l15, k contiguous ----
  short8 aq[2];
  {
    int srow = n * 64 + w * 16 + l15;
#pragma unroll
    for (int kk = 0; kk < 2; ++kk)
      aq[kk] = *(const short8*)(qp + (size_t)srow * CQ + kk * 32 + lk * 8);
  }

  // ---- scores: 8 col-tiles (4 local, 4 summary) ----
  f32x4 sc[8];
  f32x4 zero = {0.f, 0.f, 0.f, 0.f};
#pragma unroll
  for (int c = 0; c < 8; ++c) sc[c] = zero;
#pragma unroll
  for (int c = 0; c < 8; ++c) {
    int key = (c < 4) ? (n * 64 + c * 16 + l15) : (((c - 4) * 16 + l15) * 64 + 63);
    const ushort* kr = kp + (size_t)key * CQ;
#pragma unroll
    for (int kk = 0; kk < 2; ++kk) {
      short8 bk = *(const short8*)(kr + kk * 32 + lk * 8);
      sc[c] = __builtin_amdgcn_mfma_f32_16x16x32_bf16(aq[kk], bk, sc[c], 0, 0, 0);
    }
  }

  // ---- mask + scale ----
  float p[8][4];
  int qrow = w * 16 + lk * 4;
#pragma unroll
  for (int c = 0; c < 8; ++c)
#pragma unroll
    for (int r = 0; r < 4; ++r) {
      float s = sc[c][r] * 0.125f;
      bool ok = (c < 4) ? ((qrow + r) >= (c * 16 + l15)) : (((c - 4) * 16 + l15) < n);
      p[c][r] = ok ? s : -1e30f;
    }

  // ---- row softmax (row lives in 16 lanes x 8 in-lane values) ----
#pragma unroll
  for (int r = 0; r < 4; ++r) {
    float m = p[0][r];
#pragma unroll
    for (int c = 1; c < 8; ++c) m = fmaxf(m, p[c][r]);
    m = fmaxf(m, __shfl_xor(m, 1));
    m = fmaxf(m, __shfl_xor(m, 2));
    m = fmaxf(m, __shfl_xor(m, 4));
    m = fmaxf(m, __shfl_xor(m, 8));
    float sum = 0.f;
#pragma unroll
    for (int c = 0; c < 8; ++c) {
      p[c][r] = __expf(p[c][r] - m);
      sum += p[c][r];
    }
    sum += __shfl_xor(sum, 1);
    sum += __shfl_xor(sum, 2);
    sum += __shfl_xor(sum, 4);
    sum += __shfl_xor(sum, 8);
    float rs = 1.f / sum;
#pragma unroll
    for (int c = 0; c < 8; ++c) p[c][r] *= rs;
  }

  // ---- P -> LDS (D layout) then re-read as A fragments ----
  char* myP = pL[w];
#pragma unroll
  for (int c = 0; c < 8; ++c)
#pragma unroll
    for (int r = 0; r < 4; ++r) {
      uint row = lk * 4 + r;
      uint byte = row * 256 + (c * 16 + l15) * 2;
      *(short*)&myP[byte ^ ((row & 7u) << 4)] = (short)f2bf(p[c][r]);
    }
  short8 ap[4];
#pragma unroll
  for (int kk = 0; kk < 4; ++kk) {
    uint row = (uint)l15;
    uint byte = row * 256 + (kk * 32 + lk * 8) * 2;
    ap[kk] = *(const short8*)&myP[byte ^ ((row & 7u) << 4)];
  }

  // ---- PV: out[16 x 64] ----
  f32x4 ao[4];
#pragma unroll
  for (int dc = 0; dc < 4; ++dc) ao[dc] = zero;
#pragma unroll
  for (int dc = 0; dc < 4; ++dc)
#pragma unroll
    for (int kk = 0; kk < 4; ++kk) {
      uint d = dc * 16 + l15;
      uint byte = d * 256 + (kk * 32 + lk * 8) * 2;
      short8 bv = *(const short8*)&vT[byte ^ ((d & 7u) << 4)];
      ao[dc] = __builtin_amdgcn_mfma_f32_16x16x32_bf16(ap[kk], bv, ao[dc], 0, 0, 0);
    }

  // ---- write attn out [B*S][1024], col = h*64 + d ----
#pragma unroll
  for (int dc = 0; dc < 4; ++dc)
#pragma unroll
    for (int r = 0; r < 4; ++r) {
      int srow = n * 64 + w * 16 + lk * 4 + r;
      int col = h * 64 + dc * 16 + l15;
      aout[((size_t)(b * S + srow)) * 1024 + col] = f2bf(ao[dc][r]);
    }
}

// ---------------- launch ----------------
extern "C" void kernel_launch(void* const* d_in, const int* in_sizes, int n_in,
                              void* d_out, int out_size, void* d_ws, size_t ws_size,
                              hipStream_t stream) {
  const float* x = (const float*)d_in[0];
  const float* wi = (const float*)d_in[1];
  const float* bi = (const float*)d_in[2];
  const float* wo = (const float*)d_in[3];
  const float* bo = (const float*)d_in[4];
  float* out = (float*)d_out;
  char* ws = (char*)d_ws;

  ushort* xb = (ushort*)(ws);                           // 16384*1024*2 = 32MB
  ushort* wib = (ushort*)(ws + (size_t)33554432);       // 3072*1024*2  = 6MB
  ushort* wob = (ushort*)(ws + (size_t)39845888);       // 1024*1024*2  = 2MB
  ushort* qkvb = (ushort*)(ws + (size_t)41943040);      // 16384*3072*2 = 96MB
  ushort* aob = (ushort*)(ws + (size_t)142606336);      // 16384*1024*2 = 32MB

  cvt_all<<<2048, 256, 0, stream>>>(x, wi, wo, xb, wib, wob);

  // gemm1: 768 tiles (64 x 12), persistent 3 tiles/block -> 256 blocks
  gemm256p<0, 12, 3><<<256, 512, 0, stream>>>(xb, wib, bi, qkvb, 3072);
  cron_attn<<<4096, 256, 0, stream>>>(qkvb, aob);
  // gemm2: 256 tiles (64 x 4), 1 tile/block
  gemm256p<1, 4, 1><<<256, 512, 0, stream>>>(aob, wob, bo, out, 1024);
}

// Round 7
// 225.178 us; speedup vs baseline: 1.1646x; 1.1646x over previous
//
#include <hip/hip_runtime.h>
#include <stdint.h>

typedef __attribute__((ext_vector_type(8))) short short8;
typedef __attribute__((ext_vector_type(4))) short s16x4;
typedef __attribute__((ext_vector_type(4))) float f32x4;
typedef __attribute__((ext_vector_type(4))) float f4;
typedef __attribute__((ext_vector_type(4))) ushort us4;

#define AS1 __attribute__((address_space(1)))
#define AS3 __attribute__((address_space(3)))

__device__ __forceinline__ ushort f2bf(float f) {
  uint u = __builtin_bit_cast(uint, f);
  u += 0x7fffu + ((u >> 16) & 1u);
  return (ushort)(u >> 16);
}

// ---------------- fused f32 -> bf16 conversion (x, wi, wo in one launch) ----
__global__ void cvt_all(const float* __restrict__ x, const float* __restrict__ wi,
                        const float* __restrict__ wo, ushort* __restrict__ xb,
                        ushort* __restrict__ wib, ushort* __restrict__ wob) {
  const int n_x = (16384 * 1024) / 4;
  const int n_wi = (3072 * 1024) / 4;
  const int n_wo = (1024 * 1024) / 4;
  const int n_tot = n_x + n_wi + n_wo;
  int i = blockIdx.x * blockDim.x + threadIdx.x;
  int stride = gridDim.x * blockDim.x;
  for (; i < n_tot; i += stride) {
    const float* src;
    ushort* dst;
    int idx;
    if (i < n_x) {
      src = x; dst = xb; idx = i;
    } else if (i < n_x + n_wi) {
      src = wi; dst = wib; idx = i - n_x;
    } else {
      src = wo; dst = wob; idx = i - n_x - n_wi;
    }
    f4 v = ((const f4*)src)[idx];
    us4 o;
    o[0] = f2bf(v[0]); o[1] = f2bf(v[1]); o[2] = f2bf(v[2]); o[3] = f2bf(v[3]);
    ((us4*)dst)[idx] = o;
  }
}

// ---------------- 256x256-tile 8-phase GEMM: C[M,N] = A[M,K]*B[N,K]^T + bias ----
// Round-2 verified kernel (gemm1 124us): 8 waves (2M x 4N), BK=64, double-
// buffered LDS, row-XOR swizzle physical_byte = logical_byte ^ ((row&7)<<4).
// Per phase: fragment ds_reads issued BEFORE stage/barrier (complete under the
// barrier wait + other waves' MFMAs); counted vmcnt(6) only at qd==3.

__device__ __forceinline__ void stage_half(const ushort* __restrict__ g, int pitch,
                                           int row0, int k0, char* ldsbase, int tid) {
#pragma unroll
  for (int i = 0; i < 2; ++i) {
    uint chunk = i * 512 + tid;              // physical 16B chunk in 16KB half-tile
    uint Q = chunk << 4;
    uint L = Q ^ (((Q >> 7) & 7u) << 4);     // logical byte (involution, row-preserving)
    uint row = L >> 7;                       // 0..127
    uint kb = L & 127u;
    const char* gp = (const char*)(g + (size_t)(row0 + (int)row) * pitch + k0) + kb;
    char* lp = ldsbase + ((i * 512 + (tid & ~63)) << 4);  // wave-uniform base
    __builtin_amdgcn_global_load_lds((const AS1 void*)gp, (AS3 void*)lp, 16, 0, 0);
  }
}

__device__ __forceinline__ void stage_j(int j, const ushort* __restrict__ A,
                                        const ushort* __restrict__ Bw, int K,
                                        int arow0, int brow0, char* sA, char* sB, int tid) {
  int t = j >> 2, h = j & 3;
  int k0 = t << 6;
  char* base = ((h < 2) ? sB : sA) + ((t & 1) << 15) + ((h & 1) << 14);
  const ushort* g = (h < 2) ? Bw : A;
  int row0 = ((h < 2) ? brow0 : arow0) + ((h & 1) << 7);
  stage_half(g, K, row0, k0, base, tid);
}

template <int OUT_F32>
__global__ __launch_bounds__(512, 1) void gemm256(const ushort* __restrict__ A,
                                                  const ushort* __restrict__ Bw,
                                                  const float* __restrict__ bias,
                                                  void* __restrict__ Cout,
                                                  int M, int N, int K, int gn) {
  __shared__ char sA[65536];
  __shared__ char sB[65536];
  const int tid = threadIdx.x;
  const int lane = tid & 63, l15 = lane & 15, lk = lane >> 4;
  const int w = tid >> 6;
  const int wm = w >> 2, wn = w & 3;
  const int NT = K >> 6;

  // XCD-aware swizzle (gridDim.x % 8 == 0), row-major tile order within chunk
  int q8 = gridDim.x >> 3;
  int bid = blockIdx.x;
  int swz = (bid & 7) * q8 + (bid >> 3);
  int bm = swz / gn, bn = swz % gn;
  const int arow0 = bm << 8, brow0 = bn << 8;

  f32x4 acc[8][4];
  f32x4 zero = {0.f, 0.f, 0.f, 0.f};
#pragma unroll
  for (int i = 0; i < 8; ++i)
#pragma unroll
    for (int j = 0; j < 4; ++j) acc[i][j] = zero;

  // prologue: stage half-tiles 0..6 (K-tile 0 complete + 3 of K-tile 1)
#pragma unroll
  for (int j = 0; j < 7; ++j) stage_j(j, A, Bw, K, arow0, brow0, sA, sB, tid);
  asm volatile("s_waitcnt vmcnt(6)" ::: "memory");
  __builtin_amdgcn_s_barrier();

  for (int t = 0; t < NT; ++t) {
    const char* bA = sA + ((t & 1) << 15);
    const char* bB = sB + ((t & 1) << 15);
    short8 bfr[4][2];
#pragma unroll
    for (int qd = 0; qd < 4; ++qd) {
      short8 afr[2][2];
      if (qd == 0) {
#pragma unroll
        for (int ni = 0; ni < 4; ++ni)
#pragma unroll
          for (int kk = 0; kk < 2; ++kk) {
            uint row = (uint)(wn * 64 + ni * 16 + l15);
            uint byte = (row << 7) + (kk << 6) + (lk << 4);
            bfr[ni][kk] = *(const short8*)&bB[byte ^ ((row & 7u) << 4)];
          }
      }
#pragma unroll
      for (int mi = 0; mi < 2; ++mi)
#pragma unroll
        for (int kk = 0; kk < 2; ++kk) {
          uint row = (uint)(wm * 128 + (qd * 2 + mi) * 16 + l15);
          uint byte = (row << 7) + (kk << 6) + (lk << 4);
          afr[mi][kk] = *(const short8*)&bA[byte ^ ((row & 7u) << 4)];
        }
      int j = 4 * t + qd + 7;
      if (j < 4 * NT) stage_j(j, A, Bw, K, arow0, brow0, sA, sB, tid);
      if (qd == 3) {
        if (t < NT - 2) asm volatile("s_waitcnt vmcnt(6)" ::: "memory");
        else if (t == NT - 2) asm volatile("s_waitcnt vmcnt(0)" ::: "memory");
      }
      __builtin_amdgcn_s_barrier();
      asm volatile("s_waitcnt lgkmcnt(0)" ::: "memory");
      __builtin_amdgcn_s_setprio(1);
#pragma unroll
      for (int kk = 0; kk < 2; ++kk)
#pragma unroll
        for (int mi = 0; mi < 2; ++mi)
#pragma unroll
          for (int ni = 0; ni < 4; ++ni)
            acc[qd * 2 + mi][ni] = __builtin_amdgcn_mfma_f32_16x16x32_bf16(
                afr[mi][kk], bfr[ni][kk], acc[qd * 2 + mi][ni], 0, 0, 0);
      __builtin_amdgcn_s_setprio(0);
      __builtin_amdgcn_s_barrier();
    }
  }

  // epilogue: C-write (C/D layout: col=lane&15, row=(lane>>4)*4+reg)
#pragma unroll
  for (int m = 0; m < 8; ++m)
#pragma unroll
    for (int ni = 0; ni < 4; ++ni)
#pragma unroll
      for (int r = 0; r < 4; ++r) {
        int row = arow0 + wm * 128 + m * 16 + lk * 4 + r;
        int col = brow0 + wn * 64 + ni * 16 + l15;
        float v = acc[m][ni][r] + bias[col];
        if constexpr (OUT_F32)
          ((float*)Cout)[(size_t)row * N + col] = v;
        else
          ((ushort*)Cout)[(size_t)row * N + col] = f2bf(v);
      }
}

// ---------------- cron-root block-sparse attention ----------------
// qkv: [B*S][3072] bf16, cols: q = h*64+d, k = 1024 + h*64+d, v = 2048 + h*64+d
// grid = B*H*nb = 4096 blocks of 256 threads; each wave = 16 query rows.
__global__ __launch_bounds__(256) void cron_attn(const ushort* __restrict__ qkv,
                                                 ushort* __restrict__ aout) {
  const int S = 4096, CQ = 3072;
  int bid = blockIdx.x;
  int n = bid & 63;
  int h = (bid >> 6) & 15;
  int b = bid >> 10;
  int tid = threadIdx.x;
  int w = tid >> 6, lane = tid & 63, l15 = lane & 15, lk = lane >> 4;

  const ushort* qp = qkv + (size_t)b * S * CQ + h * 64;
  const ushort* kp = qp + 1024;
  const ushort* vp = qp + 2048;

  __shared__ char vT[16384];    // [64 d][128 key] bf16, swizzled 256B rows
  __shared__ char pL[4][4096];  // per-wave [16 q][128 key] bf16, swizzled

  // ---- stage V^T via register 4x4-transpose + b64 writes ----
  // thread: keys rg*4..rg*4+3 (rg = tid&31 within wave-half pattern), d-octet
  // dj*8..+7. Writes are 8B, 2 lanes/bank-pair (free, m136); swizzle XOR only
  // touches bits>=4 so 8B blocks stay intact; read side unchanged.
  {
    int rg = tid & 31;            // key group 0..31 (keys rg*4 .. rg*4+3)
    int dj = tid >> 5;            // d-octet 0..7
    short8 vv[4];
#pragma unroll
    for (int i = 0; i < 4; ++i) {
      int r = rg * 4 + i;         // concat key index 0..127
      int srow = (r < 64) ? (n * 64 + r) : ((r - 64) * 64 + 63);
      vv[i] = *(const short8*)(vp + (size_t)srow * CQ + dj * 8);
    }
#pragma unroll
    for (int j = 0; j < 8; ++j) {
      int d = dj * 8 + j;
      s16x4 o = {vv[0][j], vv[1][j], vv[2][j], vv[3][j]};
      *(s16x4*)&vT[(uint)(d * 256 + rg * 8) ^ (((uint)d & 7u) << 4)] = o;
    }
  }
  __syncthreads();

  // ---- Q fragments (A operand): row = l15, k contiguous ----
  short8 aq[2];
  {
    int srow = n * 64 + w * 16 + l15;
#pragma unroll
    for (int kk = 0; kk < 2; ++kk)
      aq[kk] = *(const short8*)(qp + (size_t)srow * CQ + kk * 32 + lk * 8);
  }

  // ---- scores: 8 col-tiles (4 local, 4 summary) ----
  f32x4 sc[8];
  f32x4 zero = {0.f, 0.f, 0.f, 0.f};
#pragma unroll
  for (int c = 0; c < 8; ++c) sc[c] = zero;
  __builtin_amdgcn_s_setprio(1);
#pragma unroll
  for (int c = 0; c < 8; ++c) {
    int key = (c < 4) ? (n * 64 + c * 16 + l15) : (((c - 4) * 16 + l15) * 64 + 63);
    const ushort* kr = kp + (size_t)key * CQ;
#pragma unroll
    for (int kk = 0; kk < 2; ++kk) {
      short8 bk = *(const short8*)(kr + kk * 32 + lk * 8);
      sc[c] = __builtin_amdgcn_mfma_f32_16x16x32_bf16(aq[kk], bk, sc[c], 0, 0, 0);
    }
  }
  __builtin_amdgcn_s_setprio(0);

  // ---- mask + scale ----
  float p[8][4];
  int qrow = w * 16 + lk * 4;
#pragma unroll
  for (int c = 0; c < 8; ++c)
#pragma unroll
    for (int r = 0; r < 4; ++r) {
      float s = sc[c][r] * 0.125f;
      bool ok = (c < 4) ? ((qrow + r) >= (c * 16 + l15)) : (((c - 4) * 16 + l15) < n);
      p[c][r] = ok ? s : -1e30f;
    }

  // ---- row softmax (row lives in 16 lanes x 8 in-lane values) ----
#pragma unroll
  for (int r = 0; r < 4; ++r) {
    float m = p[0][r];
#pragma unroll
    for (int c = 1; c < 8; ++c) m = fmaxf(m, p[c][r]);
    m = fmaxf(m, __shfl_xor(m, 1));
    m = fmaxf(m, __shfl_xor(m, 2));
    m = fmaxf(m, __shfl_xor(m, 4));
    m = fmaxf(m, __shfl_xor(m, 8));
    float sum = 0.f;
#pragma unroll
    for (int c = 0; c < 8; ++c) {
      p[c][r] = __expf(p[c][r] - m);
      sum += p[c][r];
    }
    sum += __shfl_xor(sum, 1);
    sum += __shfl_xor(sum, 2);
    sum += __shfl_xor(sum, 4);
    sum += __shfl_xor(sum, 8);
    float rs = 1.f / sum;
#pragma unroll
    for (int c = 0; c < 8; ++c) p[c][r] *= rs;
  }

  // ---- P -> LDS (D layout) then re-read as A fragments ----
  char* myP = pL[w];
#pragma unroll
  for (int c = 0; c < 8; ++c)
#pragma unroll
    for (int r = 0; r < 4; ++r) {
      uint row = lk * 4 + r;
      uint byte = row * 256 + (c * 16 + l15) * 2;
      *(short*)&myP[byte ^ ((row & 7u) << 4)] = (short)f2bf(p[c][r]);
    }
  short8 ap[4];
#pragma unroll
  for (int kk = 0; kk < 4; ++kk) {
    uint row = (uint)l15;
    uint byte = row * 256 + (kk * 32 + lk * 8) * 2;
    ap[kk] = *(const short8*)&myP[byte ^ ((row & 7u) << 4)];
  }

  // ---- PV: out[16 x 64] ----
  f32x4 ao[4];
#pragma unroll
  for (int dc = 0; dc < 4; ++dc) ao[dc] = zero;
  __builtin_amdgcn_s_setprio(1);
#pragma unroll
  for (int dc = 0; dc < 4; ++dc)
#pragma unroll
    for (int kk = 0; kk < 4; ++kk) {
      uint d = dc * 16 + l15;
      uint byte = d * 256 + (kk * 32 + lk * 8) * 2;
      short8 bv = *(const short8*)&vT[byte ^ ((d & 7u) << 4)];
      ao[dc] = __builtin_amdgcn_mfma_f32_16x16x32_bf16(ap[kk], bv, ao[dc], 0, 0, 0);
    }
  __builtin_amdgcn_s_setprio(0);

  // ---- write attn out [B*S][1024], col = h*64 + d ----
#pragma unroll
  for (int dc = 0; dc < 4; ++dc)
#pragma unroll
    for (int r = 0; r < 4; ++r) {
      int srow = n * 64 + w * 16 + lk * 4 + r;
      int col = h * 64 + dc * 16 + l15;
      aout[((size_t)(b * S + srow)) * 1024 + col] = f2bf(ao[dc][r]);
    }
}

// ---------------- launch ----------------
extern "C" void kernel_launch(void* const* d_in, const int* in_sizes, int n_in,
                              void* d_out, int out_size, void* d_ws, size_t ws_size,
                              hipStream_t stream) {
  const float* x = (const float*)d_in[0];
  const float* wi = (const float*)d_in[1];
  const float* bi = (const float*)d_in[2];
  const float* wo = (const float*)d_in[3];
  const float* bo = (const float*)d_in[4];
  float* out = (float*)d_out;
  char* ws = (char*)d_ws;

  ushort* xb = (ushort*)(ws);                           // 16384*1024*2 = 32MB
  ushort* wib = (ushort*)(ws + (size_t)33554432);       // 3072*1024*2  = 6MB
  ushort* wob = (ushort*)(ws + (size_t)39845888);       // 1024*1024*2  = 2MB
  ushort* qkvb = (ushort*)(ws + (size_t)41943040);      // 16384*3072*2 = 96MB
  ushort* aob = (ushort*)(ws + (size_t)142606336);      // 16384*1024*2 = 32MB

  cvt_all<<<2048, 256, 0, stream>>>(x, wi, wo, xb, wib, wob);

  gemm256<0><<<64 * 12, 512, 0, stream>>>(xb, wib, bi, qkvb, 16384, 3072, 1024, 12);
  cron_attn<<<4096, 256, 0, stream>>>(qkvb, aob);
  gemm256<1><<<64 * 4, 512, 0, stream>>>(aob, wob, bo, out, 16384, 1024, 1024, 4);
}

// Round 8
// 222.743 us; speedup vs baseline: 1.1774x; 1.0109x over previous
//
#include <hip/hip_runtime.h>
#include <stdint.h>

typedef __attribute__((ext_vector_type(8))) short short8;
typedef __attribute__((ext_vector_type(4))) short s16x4;
typedef __attribute__((ext_vector_type(4))) float f32x4;
typedef __attribute__((ext_vector_type(4))) float f4;
typedef __attribute__((ext_vector_type(4))) ushort us4;

#define AS1 __attribute__((address_space(1)))
#define AS3 __attribute__((address_space(3)))

__device__ __forceinline__ ushort f2bf(float f) {
  uint u = __builtin_bit_cast(uint, f);
  u += 0x7fffu + ((u >> 16) & 1u);
  return (ushort)(u >> 16);
}

// ---------------- fused f32 -> bf16 conversion (x, wi, wo in one launch) ----
__global__ void cvt_all(const float* __restrict__ x, const float* __restrict__ wi,
                        const float* __restrict__ wo, ushort* __restrict__ xb,
                        ushort* __restrict__ wib, ushort* __restrict__ wob) {
  const int n_x = (16384 * 1024) / 4;
  const int n_wi = (3072 * 1024) / 4;
  const int n_wo = (1024 * 1024) / 4;
  const int n_tot = n_x + n_wi + n_wo;
  int i = blockIdx.x * blockDim.x + threadIdx.x;
  int stride = gridDim.x * blockDim.x;
  for (; i < n_tot; i += stride) {
    const float* src;
    ushort* dst;
    int idx;
    if (i < n_x) {
      src = x; dst = xb; idx = i;
    } else if (i < n_x + n_wi) {
      src = wi; dst = wib; idx = i - n_x;
    } else {
      src = wo; dst = wob; idx = i - n_x - n_wi;
    }
    f4 v = ((const f4*)src)[idx];
    us4 o;
    o[0] = f2bf(v[0]); o[1] = f2bf(v[1]); o[2] = f2bf(v[2]); o[3] = f2bf(v[3]);
    ((us4*)dst)[idx] = o;
  }
}

// ---------------- 256x256-tile 8-phase GEMM: C[M,N] = A[M,K]*B[N,K]^T + bias ----
// Round-2 verified kernel (gemm1 124us): 8 waves (2M x 4N), BK=64, double-
// buffered LDS, row-XOR swizzle physical_byte = logical_byte ^ ((row&7)<<4).
// Per phase: fragment ds_reads issued BEFORE stage/barrier (complete under the
// barrier wait + other waves' MFMAs); counted vmcnt(6) only at qd==3.

__device__ __forceinline__ void stage_half(const ushort* __restrict__ g, int pitch,
                                           int row0, int k0, char* ldsbase, int tid) {
#pragma unroll
  for (int i = 0; i < 2; ++i) {
    uint chunk = i * 512 + tid;              // physical 16B chunk in 16KB half-tile
    uint Q = chunk << 4;
    uint L = Q ^ (((Q >> 7) & 7u) << 4);     // logical byte (involution, row-preserving)
    uint row = L >> 7;                       // 0..127
    uint kb = L & 127u;
    const char* gp = (const char*)(g + (size_t)(row0 + (int)row) * pitch + k0) + kb;
    char* lp = ldsbase + ((i * 512 + (tid & ~63)) << 4);  // wave-uniform base
    __builtin_amdgcn_global_load_lds((const AS1 void*)gp, (AS3 void*)lp, 16, 0, 0);
  }
}

__device__ __forceinline__ void stage_j(int j, const ushort* __restrict__ A,
                                        const ushort* __restrict__ Bw, int K,
                                        int arow0, int brow0, char* sA, char* sB, int tid) {
  int t = j >> 2, h = j & 3;
  int k0 = t << 6;
  char* base = ((h < 2) ? sB : sA) + ((t & 1) << 15) + ((h & 1) << 14);
  const ushort* g = (h < 2) ? Bw : A;
  int row0 = ((h < 2) ? brow0 : arow0) + ((h & 1) << 7);
  stage_half(g, K, row0, k0, base, tid);
}

template <int OUT_F32>
__global__ __launch_bounds__(512, 1) void gemm256(const ushort* __restrict__ A,
                                                  const ushort* __restrict__ Bw,
                                                  const float* __restrict__ bias,
                                                  void* __restrict__ Cout,
                                                  int M, int N, int K, int gn) {
  __shared__ char sA[65536];
  __shared__ char sB[65536];
  const int tid = threadIdx.x;
  const int lane = tid & 63, l15 = lane & 15, lk = lane >> 4;
  const int w = tid >> 6;
  const int wm = w >> 2, wn = w & 3;
  const int NT = K >> 6;

  // XCD-aware swizzle (gridDim.x % 8 == 0), row-major tile order within chunk
  int q8 = gridDim.x >> 3;
  int bid = blockIdx.x;
  int swz = (bid & 7) * q8 + (bid >> 3);
  int bm = swz / gn, bn = swz % gn;
  const int arow0 = bm << 8, brow0 = bn << 8;

  f32x4 acc[8][4];
  f32x4 zero = {0.f, 0.f, 0.f, 0.f};
#pragma unroll
  for (int i = 0; i < 8; ++i)
#pragma unroll
    for (int j = 0; j < 4; ++j) acc[i][j] = zero;

  // prologue: stage half-tiles 0..6 (K-tile 0 complete + 3 of K-tile 1)
#pragma unroll
  for (int j = 0; j < 7; ++j) stage_j(j, A, Bw, K, arow0, brow0, sA, sB, tid);
  asm volatile("s_waitcnt vmcnt(6)" ::: "memory");
  __builtin_amdgcn_s_barrier();

  for (int t = 0; t < NT; ++t) {
    const char* bA = sA + ((t & 1) << 15);
    const char* bB = sB + ((t & 1) << 15);
    short8 bfr[4][2];
#pragma unroll
    for (int qd = 0; qd < 4; ++qd) {
      short8 afr[2][2];
      if (qd == 0) {
#pragma unroll
        for (int ni = 0; ni < 4; ++ni)
#pragma unroll
          for (int kk = 0; kk < 2; ++kk) {
            uint row = (uint)(wn * 64 + ni * 16 + l15);
            uint byte = (row << 7) + (kk << 6) + (lk << 4);
            bfr[ni][kk] = *(const short8*)&bB[byte ^ ((row & 7u) << 4)];
          }
      }
#pragma unroll
      for (int mi = 0; mi < 2; ++mi)
#pragma unroll
        for (int kk = 0; kk < 2; ++kk) {
          uint row = (uint)(wm * 128 + (qd * 2 + mi) * 16 + l15);
          uint byte = (row << 7) + (kk << 6) + (lk << 4);
          afr[mi][kk] = *(const short8*)&bA[byte ^ ((row & 7u) << 4)];
        }
      int j = 4 * t + qd + 7;
      if (j < 4 * NT) stage_j(j, A, Bw, K, arow0, brow0, sA, sB, tid);
      if (qd == 3) {
        if (t < NT - 2) asm volatile("s_waitcnt vmcnt(6)" ::: "memory");
        else if (t == NT - 2) asm volatile("s_waitcnt vmcnt(0)" ::: "memory");
      }
      __builtin_amdgcn_s_barrier();
      asm volatile("s_waitcnt lgkmcnt(0)" ::: "memory");
      __builtin_amdgcn_s_setprio(1);
#pragma unroll
      for (int kk = 0; kk < 2; ++kk)
#pragma unroll
        for (int mi = 0; mi < 2; ++mi)
#pragma unroll
          for (int ni = 0; ni < 4; ++ni)
            acc[qd * 2 + mi][ni] = __builtin_amdgcn_mfma_f32_16x16x32_bf16(
                afr[mi][kk], bfr[ni][kk], acc[qd * 2 + mi][ni], 0, 0, 0);
      __builtin_amdgcn_s_setprio(0);
      __builtin_amdgcn_s_barrier();
    }
  }

  // epilogue: C-write (C/D layout: col=lane&15, row=(lane>>4)*4+reg)
#pragma unroll
  for (int m = 0; m < 8; ++m)
#pragma unroll
    for (int ni = 0; ni < 4; ++ni)
#pragma unroll
      for (int r = 0; r < 4; ++r) {
        int row = arow0 + wm * 128 + m * 16 + lk * 4 + r;
        int col = brow0 + wn * 64 + ni * 16 + l15;
        float v = acc[m][ni][r] + bias[col];
        if constexpr (OUT_F32)
          ((float*)Cout)[(size_t)row * N + col] = v;
        else
          ((ushort*)Cout)[(size_t)row * N + col] = f2bf(v);
      }
}

// ---------------- cron-root block-sparse attention ----------------
// qkv: [B*S][3072] bf16, cols: q = h*64+d, k = 1024 + h*64+d, v = 2048 + h*64+d
// grid = B*H*nb = 4096 blocks of 256 threads; each wave = 16 query rows.
// Latency plan: issue V + Q + local-K global loads up front; V transpose-write
// overlaps K latency; the ONLY barrier sits just before PV (vT's sole consumer),
// so QK^T + softmax + P-roundtrip (per-wave LDS) run under V staging of other
// waves. Summary-K tiles are L2-warm (shared by 64 blocks) and load in-loop.
__global__ __launch_bounds__(256) void cron_attn(const ushort* __restrict__ qkv,
                                                 ushort* __restrict__ aout) {
  const int S = 4096, CQ = 3072;
  int bid = blockIdx.x;
  int n = bid & 63;
  int h = (bid >> 6) & 15;
  int b = bid >> 10;
  int tid = threadIdx.x;
  int w = tid >> 6, lane = tid & 63, l15 = lane & 15, lk = lane >> 4;

  const ushort* qp = qkv + (size_t)b * S * CQ + h * 64;
  const ushort* kp = qp + 1024;
  const ushort* vp = qp + 2048;

  __shared__ char vT[16384];    // [64 d][128 key] bf16, swizzled 256B rows
  __shared__ char pL[4][4096];  // per-wave [16 q][128 key] bf16, swizzled

  // ---- issue V loads (register transpose source) ----
  int rg = tid & 31;            // key group 0..31 (keys rg*4 .. rg*4+3)
  int dj = tid >> 5;            // d-octet 0..7
  short8 vv[4];
#pragma unroll
  for (int i = 0; i < 4; ++i) {
    int r = rg * 4 + i;         // concat key index 0..127
    int srow = (r < 64) ? (n * 64 + r) : ((r - 64) * 64 + 63);
    vv[i] = *(const short8*)(vp + (size_t)srow * CQ + dj * 8);
  }

  // ---- issue Q + local-K loads (cold HBM) before V transpose-writes ----
  short8 aq[2];
  {
    int srow = n * 64 + w * 16 + l15;
#pragma unroll
    for (int kk = 0; kk < 2; ++kk)
      aq[kk] = *(const short8*)(qp + (size_t)srow * CQ + kk * 32 + lk * 8);
  }
  short8 bkl[4][2];
#pragma unroll
  for (int c = 0; c < 4; ++c) {
    const ushort* kr = kp + (size_t)(n * 64 + c * 16 + l15) * CQ;
#pragma unroll
    for (int kk = 0; kk < 2; ++kk)
      bkl[c][kk] = *(const short8*)(kr + kk * 32 + lk * 8);
  }

  // ---- V transpose -> LDS (waits only on vv) ----
#pragma unroll
  for (int j = 0; j < 8; ++j) {
    int d = dj * 8 + j;
    s16x4 o = {vv[0][j], vv[1][j], vv[2][j], vv[3][j]};
    *(s16x4*)&vT[(uint)(d * 256 + rg * 8) ^ (((uint)d & 7u) << 4)] = o;
  }

  // ---- scores: 4 local tiles from registers, 4 summary tiles in-loop ----
  f32x4 sc[8];
  f32x4 zero = {0.f, 0.f, 0.f, 0.f};
#pragma unroll
  for (int c = 0; c < 8; ++c) sc[c] = zero;
  __builtin_amdgcn_s_setprio(1);
#pragma unroll
  for (int c = 0; c < 4; ++c)
#pragma unroll
    for (int kk = 0; kk < 2; ++kk)
      sc[c] = __builtin_amdgcn_mfma_f32_16x16x32_bf16(aq[kk], bkl[c][kk], sc[c], 0, 0, 0);
#pragma unroll
  for (int c = 4; c < 8; ++c) {
    const ushort* kr = kp + (size_t)(((c - 4) * 16 + l15) * 64 + 63) * CQ;
#pragma unroll
    for (int kk = 0; kk < 2; ++kk) {
      short8 bk = *(const short8*)(kr + kk * 32 + lk * 8);
      sc[c] = __builtin_amdgcn_mfma_f32_16x16x32_bf16(aq[kk], bk, sc[c], 0, 0, 0);
    }
  }
  __builtin_amdgcn_s_setprio(0);

  // ---- mask + scale ----
  float p[8][4];
  int qrow = w * 16 + lk * 4;
#pragma unroll
  for (int c = 0; c < 8; ++c)
#pragma unroll
    for (int r = 0; r < 4; ++r) {
      float s = sc[c][r] * 0.125f;
      bool ok = (c < 4) ? ((qrow + r) >= (c * 16 + l15)) : (((c - 4) * 16 + l15) < n);
      p[c][r] = ok ? s : -1e30f;
    }

  // ---- row softmax (row lives in 16 lanes x 8 in-lane values) ----
#pragma unroll
  for (int r = 0; r < 4; ++r) {
    float m = p[0][r];
#pragma unroll
    for (int c = 1; c < 8; ++c) m = fmaxf(m, p[c][r]);
    m = fmaxf(m, __shfl_xor(m, 1));
    m = fmaxf(m, __shfl_xor(m, 2));
    m = fmaxf(m, __shfl_xor(m, 4));
    m = fmaxf(m, __shfl_xor(m, 8));
    float sum = 0.f;
#pragma unroll
    for (int c = 0; c < 8; ++c) {
      p[c][r] = __expf(p[c][r] - m);
      sum += p[c][r];
    }
    sum += __shfl_xor(sum, 1);
    sum += __shfl_xor(sum, 2);
    sum += __shfl_xor(sum, 4);
    sum += __shfl_xor(sum, 8);
    float rs = 1.f / sum;
#pragma unroll
    for (int c = 0; c < 8; ++c) p[c][r] *= rs;
  }

  // ---- P -> per-wave LDS (no cross-wave sync needed) then A fragments ----
  char* myP = pL[w];
#pragma unroll
  for (int c = 0; c < 8; ++c)
#pragma unroll
    for (int r = 0; r < 4; ++r) {
      uint row = lk * 4 + r;
      uint byte = row * 256 + (c * 16 + l15) * 2;
      *(short*)&myP[byte ^ ((row & 7u) << 4)] = (short)f2bf(p[c][r]);
    }
  short8 ap[4];
#pragma unroll
  for (int kk = 0; kk < 4; ++kk) {
    uint row = (uint)l15;
    uint byte = row * 256 + (kk * 32 + lk * 8) * 2;
    ap[kk] = *(const short8*)&myP[byte ^ ((row & 7u) << 4)];
  }

  // ---- barrier: vT complete across all waves, then PV ----
  __syncthreads();

  f32x4 ao[4];
#pragma unroll
  for (int dc = 0; dc < 4; ++dc) ao[dc] = zero;
  __builtin_amdgcn_s_setprio(1);
#pragma unroll
  for (int dc = 0; dc < 4; ++dc)
#pragma unroll
    for (int kk = 0; kk < 4; ++kk) {
      uint d = dc * 16 + l15;
      uint byte = d * 256 + (kk * 32 + lk * 8) * 2;
      short8 bv = *(const short8*)&vT[byte ^ ((d & 7u) << 4)];
      ao[dc] = __builtin_amdgcn_mfma_f32_16x16x32_bf16(ap[kk], bv, ao[dc], 0, 0, 0);
    }
  __builtin_amdgcn_s_setprio(0);

  // ---- write attn out [B*S][1024], col = h*64 + d ----
#pragma unroll
  for (int dc = 0; dc < 4; ++dc)
#pragma unroll
    for (int r = 0; r < 4; ++r) {
      int srow = n * 64 + w * 16 + lk * 4 + r;
      int col = h * 64 + dc * 16 + l15;
      aout[((size_t)(b * S + srow)) * 1024 + col] = f2bf(ao[dc][r]);
    }
}

// ---------------- launch ----------------
extern "C" void kernel_launch(void* const* d_in, const int* in_sizes, int n_in,
                              void* d_out, int out_size, void* d_ws, size_t ws_size,
                              hipStream_t stream) {
  const float* x = (const float*)d_in[0];
  const float* wi = (const float*)d_in[1];
  const float* bi = (const float*)d_in[2];
  const float* wo = (const float*)d_in[3];
  const float* bo = (const float*)d_in[4];
  float* out = (float*)d_out;
  char* ws = (char*)d_ws;

  ushort* xb = (ushort*)(ws);                           // 16384*1024*2 = 32MB
  ushort* wib = (ushort*)(ws + (size_t)33554432);       // 3072*1024*2  = 6MB
  ushort* wob = (ushort*)(ws + (size_t)39845888);       // 1024*1024*2  = 2MB
  ushort* qkvb = (ushort*)(ws + (size_t)41943040);      // 16384*3072*2 = 96MB
  ushort* aob = (ushort*)(ws + (size_t)142606336);      // 16384*1024*2 = 32MB

  cvt_all<<<2048, 256, 0, stream>>>(x, wi, wo, xb, wib, wob);

  gemm256<0><<<64 * 12, 512, 0, stream>>>(xb, wib, bi, qkvb, 16384, 3072, 1024, 12);
  cron_attn<<<4096, 256, 0, stream>>>(qkvb, aob);
  gemm256<1><<<64 * 4, 512, 0, stream>>>(aob, wob, bo, out, 16384, 1024, 1024, 4);
}

// Round 9
// 222.281 us; speedup vs baseline: 1.1798x; 1.0021x over previous
//
#include <hip/hip_runtime.h>
#include <stdint.h>

typedef __attribute__((ext_vector_type(8))) short short8;
typedef __attribute__((ext_vector_type(4))) short s16x4;
typedef __attribute__((ext_vector_type(4))) float f32x4;
typedef __attribute__((ext_vector_type(4))) float f4;
typedef __attribute__((ext_vector_type(4))) ushort us4;
typedef __attribute__((ext_vector_type(4))) uint ui4;

#define AS1 __attribute__((address_space(1)))
#define AS3 __attribute__((address_space(3)))

__device__ __forceinline__ ushort f2bf(float f) {
  uint u = __builtin_bit_cast(uint, f);
  u += 0x7fffu + ((u >> 16) & 1u);
  return (ushort)(u >> 16);
}

// ---------------- fused f32 -> bf16 conversion (x, wi, wo in one launch) ----
__global__ void cvt_all(const float* __restrict__ x, const float* __restrict__ wi,
                        const float* __restrict__ wo, ushort* __restrict__ xb,
                        ushort* __restrict__ wib, ushort* __restrict__ wob) {
  const int n_x = (16384 * 1024) / 4;
  const int n_wi = (3072 * 1024) / 4;
  const int n_wo = (1024 * 1024) / 4;
  const int n_tot = n_x + n_wi + n_wo;
  int i = blockIdx.x * blockDim.x + threadIdx.x;
  int stride = gridDim.x * blockDim.x;
  for (; i < n_tot; i += stride) {
    const float* src;
    ushort* dst;
    int idx;
    if (i < n_x) {
      src = x; dst = xb; idx = i;
    } else if (i < n_x + n_wi) {
      src = wi; dst = wib; idx = i - n_x;
    } else {
      src = wo; dst = wob; idx = i - n_x - n_wi;
    }
    f4 v = ((const f4*)src)[idx];
    us4 o;
    o[0] = f2bf(v[0]); o[1] = f2bf(v[1]); o[2] = f2bf(v[2]); o[3] = f2bf(v[3]);
    ((us4*)dst)[idx] = o;
  }
}

// ---------------- 256x256-tile 8-phase GEMM: C[M,N] = A[M,K]*B[N,K]^T + bias ----
// Round-2 verified kernel (gemm1 124us, 4x-confirmed K=1024 operating point):
// 8 waves (2M x 4N), BK=64, double-buffered LDS, row-XOR swizzle
// physical_byte = logical_byte ^ ((row&7)<<4). Per phase: fragment ds_reads
// issued BEFORE stage/barrier; counted vmcnt(6) only at qd==3.

__device__ __forceinline__ void stage_half(const ushort* __restrict__ g, int pitch,
                                           int row0, int k0, char* ldsbase, int tid) {
#pragma unroll
  for (int i = 0; i < 2; ++i) {
    uint chunk = i * 512 + tid;              // physical 16B chunk in 16KB half-tile
    uint Q = chunk << 4;
    uint L = Q ^ (((Q >> 7) & 7u) << 4);     // logical byte (involution, row-preserving)
    uint row = L >> 7;                       // 0..127
    uint kb = L & 127u;
    const char* gp = (const char*)(g + (size_t)(row0 + (int)row) * pitch + k0) + kb;
    char* lp = ldsbase + ((i * 512 + (tid & ~63)) << 4);  // wave-uniform base
    __builtin_amdgcn_global_load_lds((const AS1 void*)gp, (AS3 void*)lp, 16, 0, 0);
  }
}

__device__ __forceinline__ void stage_j(int j, const ushort* __restrict__ A,
                                        const ushort* __restrict__ Bw, int K,
                                        int arow0, int brow0, char* sA, char* sB, int tid) {
  int t = j >> 2, h = j & 3;
  int k0 = t << 6;
  char* base = ((h < 2) ? sB : sA) + ((t & 1) << 15) + ((h & 1) << 14);
  const ushort* g = (h < 2) ? Bw : A;
  int row0 = ((h < 2) ? brow0 : arow0) + ((h & 1) << 7);
  stage_half(g, K, row0, k0, base, tid);
}

template <int OUT_F32>
__global__ __launch_bounds__(512, 1) void gemm256(const ushort* __restrict__ A,
                                                  const ushort* __restrict__ Bw,
                                                  const float* __restrict__ bias,
                                                  void* __restrict__ Cout,
                                                  int M, int N, int K, int gn) {
  __shared__ char sA[65536];
  __shared__ char sB[65536];
  const int tid = threadIdx.x;
  const int lane = tid & 63, l15 = lane & 15, lk = lane >> 4;
  const int w = tid >> 6;
  const int wm = w >> 2, wn = w & 3;
  const int NT = K >> 6;

  // XCD-aware swizzle (gridDim.x % 8 == 0), row-major tile order within chunk
  int q8 = gridDim.x >> 3;
  int bid = blockIdx.x;
  int swz = (bid & 7) * q8 + (bid >> 3);
  int bm = swz / gn, bn = swz % gn;
  const int arow0 = bm << 8, brow0 = bn << 8;

  f32x4 acc[8][4];
  f32x4 zero = {0.f, 0.f, 0.f, 0.f};
#pragma unroll
  for (int i = 0; i < 8; ++i)
#pragma unroll
    for (int j = 0; j < 4; ++j) acc[i][j] = zero;

  // prologue: stage half-tiles 0..6 (K-tile 0 complete + 3 of K-tile 1)
#pragma unroll
  for (int j = 0; j < 7; ++j) stage_j(j, A, Bw, K, arow0, brow0, sA, sB, tid);
  asm volatile("s_waitcnt vmcnt(6)" ::: "memory");
  __builtin_amdgcn_s_barrier();

  for (int t = 0; t < NT; ++t) {
    const char* bA = sA + ((t & 1) << 15);
    const char* bB = sB + ((t & 1) << 15);
    short8 bfr[4][2];
#pragma unroll
    for (int qd = 0; qd < 4; ++qd) {
      short8 afr[2][2];
      if (qd == 0) {
#pragma unroll
        for (int ni = 0; ni < 4; ++ni)
#pragma unroll
          for (int kk = 0; kk < 2; ++kk) {
            uint row = (uint)(wn * 64 + ni * 16 + l15);
            uint byte = (row << 7) + (kk << 6) + (lk << 4);
            bfr[ni][kk] = *(const short8*)&bB[byte ^ ((row & 7u) << 4)];
          }
      }
#pragma unroll
      for (int mi = 0; mi < 2; ++mi)
#pragma unroll
        for (int kk = 0; kk < 2; ++kk) {
          uint row = (uint)(wm * 128 + (qd * 2 + mi) * 16 + l15);
          uint byte = (row << 7) + (kk << 6) + (lk << 4);
          afr[mi][kk] = *(const short8*)&bA[byte ^ ((row & 7u) << 4)];
        }
      int j = 4 * t + qd + 7;
      if (j < 4 * NT) stage_j(j, A, Bw, K, arow0, brow0, sA, sB, tid);
      if (qd == 3) {
        if (t < NT - 2) asm volatile("s_waitcnt vmcnt(6)" ::: "memory");
        else if (t == NT - 2) asm volatile("s_waitcnt vmcnt(0)" ::: "memory");
      }
      __builtin_amdgcn_s_barrier();
      asm volatile("s_waitcnt lgkmcnt(0)" ::: "memory");
      __builtin_amdgcn_s_setprio(1);
#pragma unroll
      for (int kk = 0; kk < 2; ++kk)
#pragma unroll
        for (int mi = 0; mi < 2; ++mi)
#pragma unroll
          for (int ni = 0; ni < 4; ++ni)
            acc[qd * 2 + mi][ni] = __builtin_amdgcn_mfma_f32_16x16x32_bf16(
                afr[mi][kk], bfr[ni][kk], acc[qd * 2 + mi][ni], 0, 0, 0);
      __builtin_amdgcn_s_setprio(0);
      __builtin_amdgcn_s_barrier();
    }
  }

  // epilogue: C-write (C/D layout: col=lane&15, row=(lane>>4)*4+reg)
#pragma unroll
  for (int m = 0; m < 8; ++m)
#pragma unroll
    for (int ni = 0; ni < 4; ++ni)
#pragma unroll
      for (int r = 0; r < 4; ++r) {
        int row = arow0 + wm * 128 + m * 16 + lk * 4 + r;
        int col = brow0 + wn * 64 + ni * 16 + l15;
        float v = acc[m][ni][r] + bias[col];
        if constexpr (OUT_F32)
          ((float*)Cout)[(size_t)row * N + col] = v;
        else
          ((ushort*)Cout)[(size_t)row * N + col] = f2bf(v);
      }
}

// ---------------- cron-root block-sparse attention (swapped-QK, T12) -------
// qkv: [B*S][3072] bf16; grid = B*H*nb = 4096 blocks of 256 threads;
// each wave = 16 query rows.  QK^T computed SWAPPED: sc[c] = mfma(K,Q) so
// D[key=c*16+lk*4+r][q=l15] — each lane owns a full P-row (q=l15, 32 keys
// in-lane): softmax = 2 shuffles; P redistributed to PV A-fragments fully
// in-register (no P LDS roundtrip).  PV A-frag ap[kk] elem e = key
// kk*32+lk*8+e of q=l15: source tile c_s = kk*2+(lk>>1) (uniform in e),
// elems 0..3 from lane (l15, (lk&1)*2) regs 0..3, elems 4..7 from lane
// (l15, (lk&1)*2+1) regs 0..3 — 8 shfl + 4 selects per kk.
__global__ __launch_bounds__(256) void cron_attn(const ushort* __restrict__ qkv,
                                                 ushort* __restrict__ aout) {
  const int S = 4096, CQ = 3072;
  int bid = blockIdx.x;
  int n = bid & 63;
  int h = (bid >> 6) & 15;
  int b = bid >> 10;
  int tid = threadIdx.x;
  int w = tid >> 6, lane = tid & 63, l15 = lane & 15, lk = lane >> 4;

  const ushort* qp = qkv + (size_t)b * S * CQ + h * 64;
  const ushort* kp = qp + 1024;
  const ushort* vp = qp + 2048;

  __shared__ char vT[16384];    // [64 d][128 key] bf16, swizzled 256B rows

  // ---- issue V loads (register transpose source) ----
  int rg = tid & 31;            // key group 0..31 (keys rg*4 .. rg*4+3)
  int dj = tid >> 5;            // d-octet 0..7
  short8 vv[4];
#pragma unroll
  for (int i = 0; i < 4; ++i) {
    int r = rg * 4 + i;         // concat key index 0..127
    int srow = (r < 64) ? (n * 64 + r) : ((r - 64) * 64 + 63);
    vv[i] = *(const short8*)(vp + (size_t)srow * CQ + dj * 8);
  }

  // ---- issue Q + local-K loads before V transpose-writes (hide K latency) --
  short8 aq[2];
  {
    int srow = n * 64 + w * 16 + l15;
#pragma unroll
    for (int kk = 0; kk < 2; ++kk)
      aq[kk] = *(const short8*)(qp + (size_t)srow * CQ + kk * 32 + lk * 8);
  }
  short8 bkl[4][2];
#pragma unroll
  for (int c = 0; c < 4; ++c) {
    const ushort* kr = kp + (size_t)(n * 64 + c * 16 + l15) * CQ;
#pragma unroll
    for (int kk = 0; kk < 2; ++kk)
      bkl[c][kk] = *(const short8*)(kr + kk * 32 + lk * 8);
  }

  // ---- V transpose -> LDS (waits only on vv) ----
#pragma unroll
  for (int j = 0; j < 8; ++j) {
    int d = dj * 8 + j;
    s16x4 o = {vv[0][j], vv[1][j], vv[2][j], vv[3][j]};
    *(s16x4*)&vT[(uint)(d * 256 + rg * 8) ^ (((uint)d & 7u) << 4)] = o;
  }

  // ---- scores, SWAPPED operands: sc[c] = mfma(K_c, Q) ----
  f32x4 sc[8];
  f32x4 zero = {0.f, 0.f, 0.f, 0.f};
#pragma unroll
  for (int c = 0; c < 8; ++c) sc[c] = zero;
  __builtin_amdgcn_s_setprio(1);
#pragma unroll
  for (int c = 0; c < 4; ++c)
#pragma unroll
    for (int kk = 0; kk < 2; ++kk)
      sc[c] = __builtin_amdgcn_mfma_f32_16x16x32_bf16(bkl[c][kk], aq[kk], sc[c], 0, 0, 0);
#pragma unroll
  for (int c = 4; c < 8; ++c) {
    const ushort* kr = kp + (size_t)(((c - 4) * 16 + l15) * 64 + 63) * CQ;
#pragma unroll
    for (int kk = 0; kk < 2; ++kk) {
      short8 bk = *(const short8*)(kr + kk * 32 + lk * 8);
      sc[c] = __builtin_amdgcn_mfma_f32_16x16x32_bf16(bk, aq[kk], sc[c], 0, 0, 0);
    }
  }
  __builtin_amdgcn_s_setprio(0);

  // ---- mask + scale: p[c][r] = P[key=c*16+lk*4+r][q=l15], q_block=w*16+l15 --
  float p[8][4];
  int qg = w * 16 + l15;
#pragma unroll
  for (int c = 0; c < 8; ++c)
#pragma unroll
    for (int r = 0; r < 4; ++r) {
      float s = sc[c][r] * 0.125f;
      bool ok = (c < 4) ? (qg >= (c * 16 + lk * 4 + r)) : (((c - 4) * 16 + lk * 4 + r) < n);
      p[c][r] = ok ? s : -1e30f;
    }

  // ---- row softmax: 32 in-lane + lanes l15^16/^32 (2 shuffles each) ----
  {
    float m = p[0][0];
#pragma unroll
    for (int c = 0; c < 8; ++c)
#pragma unroll
      for (int r = 0; r < 4; ++r) m = fmaxf(m, p[c][r]);
    m = fmaxf(m, __shfl_xor(m, 16));
    m = fmaxf(m, __shfl_xor(m, 32));
    float sum = 0.f;
#pragma unroll
    for (int c = 0; c < 8; ++c)
#pragma unroll
      for (int r = 0; r < 4; ++r) {
        p[c][r] = __expf(p[c][r] - m);
        sum += p[c][r];
      }
    sum += __shfl_xor(sum, 16);
    sum += __shfl_xor(sum, 32);
    float rs = 1.f / sum;
#pragma unroll
    for (int c = 0; c < 8; ++c)
#pragma unroll
      for (int r = 0; r < 4; ++r) p[c][r] *= rs;
  }

  // ---- pack P rows to bf16 dwords, in-register gather -> PV A-fragments ----
  uint pkd[8][2];
#pragma unroll
  for (int c = 0; c < 8; ++c) {
    pkd[c][0] = (uint)f2bf(p[c][0]) | ((uint)f2bf(p[c][1]) << 16);
    pkd[c][1] = (uint)f2bf(p[c][2]) | ((uint)f2bf(p[c][3]) << 16);
  }
  int hb = lk >> 1;                 // selects tile parity
  int s0 = l15 + ((lk & 1) * 2) * 16;  // source lane for elems 0..3
  int s1 = s0 + 16;                 // source lane for elems 4..7
  short8 ap[4];
#pragma unroll
  for (int kk = 0; kk < 4; ++kk) {
    uint e0 = __shfl((int)pkd[kk * 2][0], s0), o0 = __shfl((int)pkd[kk * 2 + 1][0], s0);
    uint e1 = __shfl((int)pkd[kk * 2][1], s0), o1 = __shfl((int)pkd[kk * 2 + 1][1], s0);
    uint e2 = __shfl((int)pkd[kk * 2][0], s1), o2 = __shfl((int)pkd[kk * 2 + 1][0], s1);
    uint e3 = __shfl((int)pkd[kk * 2][1], s1), o3 = __shfl((int)pkd[kk * 2 + 1][1], s1);
    ui4 dw = {hb ? o0 : e0, hb ? o1 : e1, hb ? o2 : e2, hb ? o3 : e3};
    ap[kk] = __builtin_bit_cast(short8, dw);
  }

  // ---- barrier: vT complete across all waves, then PV ----
  __syncthreads();

  f32x4 ao[4];
#pragma unroll
  for (int dc = 0; dc < 4; ++dc) ao[dc] = zero;
  __builtin_amdgcn_s_setprio(1);
#pragma unroll
  for (int dc = 0; dc < 4; ++dc)
#pragma unroll
    for (int kk = 0; kk < 4; ++kk) {
      uint d = dc * 16 + l15;
      uint byte = d * 256 + (kk * 32 + lk * 8) * 2;
      short8 bv = *(const short8*)&vT[byte ^ ((d & 7u) << 4)];
      ao[dc] = __builtin_amdgcn_mfma_f32_16x16x32_bf16(ap[kk], bv, ao[dc], 0, 0, 0);
    }
  __builtin_amdgcn_s_setprio(0);

  // ---- write attn out [B*S][1024]: row q=w*16+lk*4+r, col=h*64+dc*16+l15 ----
#pragma unroll
  for (int dc = 0; dc < 4; ++dc)
#pragma unroll
    for (int r = 0; r < 4; ++r) {
      int srow = n * 64 + w * 16 + lk * 4 + r;
      int col = h * 64 + dc * 16 + l15;
      aout[((size_t)(b * S + srow)) * 1024 + col] = f2bf(ao[dc][r]);
    }
}

// ---------------- launch ----------------
extern "C" void kernel_launch(void* const* d_in, const int* in_sizes, int n_in,
                              void* d_out, int out_size, void* d_ws, size_t ws_size,
                              hipStream_t stream) {
  const float* x = (const float*)d_in[0];
  const float* wi = (const float*)d_in[1];
  const float* bi = (const float*)d_in[2];
  const float* wo = (const float*)d_in[3];
  const float* bo = (const float*)d_in[4];
  float* out = (float*)d_out;
  char* ws = (char*)d_ws;

  ushort* xb = (ushort*)(ws);                           // 16384*1024*2 = 32MB
  ushort* wib = (ushort*)(ws + (size_t)33554432);       // 3072*1024*2  = 6MB
  ushort* wob = (ushort*)(ws + (size_t)39845888);       // 1024*1024*2  = 2MB
  ushort* qkvb = (ushort*)(ws + (size_t)41943040);      // 16384*3072*2 = 96MB
  ushort* aob = (ushort*)(ws + (size_t)142606336);      // 16384*1024*2 = 32MB

  cvt_all<<<2048, 256, 0, stream>>>(x, wi, wo, xb, wib, wob);

  gemm256<0><<<64 * 12, 512, 0, stream>>>(xb, wib, bi, qkvb, 16384, 3072, 1024, 12);
  cron_attn<<<4096, 256, 0, stream>>>(qkvb, aob);
  gemm256<1><<<64 * 4, 512, 0, stream>>>(aob, wob, bo, out, 16384, 1024, 1024, 4);
}